// Round 3
// baseline (620.766 us; speedup 1.0000x reference)
//
#include <hip/hip_runtime.h>
#include <hip/hip_bf16.h>

// ---------------------------------------------------------------------------
// GCN link predictor:
//   dinv[v] = rsqrt(indeg(v)+1)
//   g  = (X @ W) * dinv[row]            (fused in GEMM epilogue)
//   z  = relu(dinv[v]*(g[v] + sum_{s->v} g[s]) + b)   (CSR gather, fused)
//   out[e] = dot(z2[s_e], z2[d_e])
// CSR (edges sorted by dst) built per call: histogram -> scan -> scatter.
// ---------------------------------------------------------------------------

__global__ __launch_bounds__(256) void k_zero(int* __restrict__ p, int n) {
    int i = blockIdx.x * 256 + threadIdx.x;
    if (i < n) p[i] = 0;
}

__global__ __launch_bounds__(256) void k_hist(const int* __restrict__ dst,
                                              int* __restrict__ cnt, int E) {
    int e = blockIdx.x * 256 + threadIdx.x;
    if (e < E) atomicAdd(&cnt[dst[e]], 1);
}

// block-level inclusive scan -> exclusive row_start + block sums
__global__ __launch_bounds__(1024) void k_scan1(const int* __restrict__ cnt,
                                                int* __restrict__ row_start,
                                                int* __restrict__ bsum, int n) {
    __shared__ int sh[1024];
    int tid = threadIdx.x;
    int i = blockIdx.x * 1024 + tid;
    int v = (i < n) ? cnt[i] : 0;
    sh[tid] = v;
    __syncthreads();
    for (int off = 1; off < 1024; off <<= 1) {
        int t = (tid >= off) ? sh[tid - off] : 0;
        __syncthreads();
        sh[tid] += t;
        __syncthreads();
    }
    if (i < n) row_start[i] = sh[tid] - v;
    if (tid == 1023) bsum[blockIdx.x] = sh[tid];
}

// exclusive scan of block sums (nb <= 1024)
__global__ __launch_bounds__(1024) void k_scan2(int* __restrict__ bsum, int nb) {
    __shared__ int sh[1024];
    int tid = threadIdx.x;
    int v = (tid < nb) ? bsum[tid] : 0;
    sh[tid] = v;
    __syncthreads();
    for (int off = 1; off < 1024; off <<= 1) {
        int t = (tid >= off) ? sh[tid - off] : 0;
        __syncthreads();
        sh[tid] += t;
        __syncthreads();
    }
    if (tid < nb) bsum[tid] = sh[tid] - v;
}

// add block offsets + compute dinv = rsqrt(deg+1)  (deg includes self loop)
__global__ __launch_bounds__(256) void k_scan3(int* __restrict__ row_start,
                                               const int* __restrict__ bsum,
                                               const int* __restrict__ cnt,
                                               float* __restrict__ dinv, int n) {
    int i = blockIdx.x * 256 + threadIdx.x;
    if (i < n) {
        row_start[i] += bsum[i >> 10];
        dinv[i] = rsqrtf((float)cnt[i] + 1.0f);
    }
}

__global__ __launch_bounds__(256) void k_scatter(const int* __restrict__ src,
                                                 const int* __restrict__ dst,
                                                 const int* __restrict__ row_start,
                                                 int* __restrict__ fill,
                                                 int* __restrict__ srcs, int E) {
    int e = blockIdx.x * 256 + threadIdx.x;
    if (e < E) {
        int d = dst[e];
        int p = row_start[d] + atomicAdd(&fill[d], 1);
        srcs[p] = src[e];
    }
}

// ---------------------------------------------------------------------------
// GEMM: G[r][c] = dinv[r] * sum_k X[r][k]*W[k][c]    (N x 128) @ (128 x 128)
// Block: 64 rows x 128 cols, 256 threads; thread tile 4 rows x 8 cols
// (cols c0..c0+3 and c0+64..c0+67 -> 2-way LDS bank alias only = free).
// W staged in 32-k chunks (16 KB LDS). A broadcast-loaded from global.
// __launch_bounds__(256,4) caps VGPRs at 128 -> no spill (R1 spilled at 256).
// A-loads software-pipelined (prefetch k4+4 while FMAing k4) so the per-iter
// vmcnt wait overlaps with compute.
// ---------------------------------------------------------------------------
__global__ __launch_bounds__(256, 4) void k_gemm_scale(const float* __restrict__ X,
                                                       const float* __restrict__ W,
                                                       const float* __restrict__ dinv,
                                                       float* __restrict__ G, int n) {
    __shared__ float Wl[32 * 128];
    const int tid = threadIdx.x;
    const int colgrp = tid & 15;   // 16 col groups
    const int rowgrp = tid >> 4;   // 16 row groups
    const int r0 = blockIdx.x * 64 + rowgrp * 4;
    const int c0 = colgrp * 4;     // second col block at c0+64

    // clamped row pointers (clamp once, reuse)
    const float* Xr[4];
#pragma unroll
    for (int i = 0; i < 4; ++i) {
        int r = r0 + i;
        if (r >= n) r = n - 1;
        Xr[i] = X + (size_t)r * 128;
    }

    float acc[4][8] = {};

    for (int kc = 0; kc < 128; kc += 32) {
        {
            const float4* W4 = (const float4*)(W + (size_t)kc * 128);
            float4* Wl4 = (float4*)Wl;
#pragma unroll
            for (int it = 0; it < 4; ++it)
                Wl4[it * 256 + tid] = W4[it * 256 + tid];
        }
        __syncthreads();

        float4 a_cur[4], a_nxt[4];
#pragma unroll
        for (int i = 0; i < 4; ++i)
            a_cur[i] = *(const float4*)(Xr[i] + kc);

#pragma unroll 1
        for (int k4 = 0; k4 < 28; k4 += 4) {
#pragma unroll
            for (int i = 0; i < 4; ++i)
                a_nxt[i] = *(const float4*)(Xr[i] + kc + k4 + 4);
#pragma unroll
            for (int kk = 0; kk < 4; ++kk) {
                float4 b0 = *(const float4*)(Wl + (k4 + kk) * 128 + c0);
                float4 b1 = *(const float4*)(Wl + (k4 + kk) * 128 + c0 + 64);
#pragma unroll
                for (int i = 0; i < 4; ++i) {
                    float av = (kk == 0) ? a_cur[i].x : (kk == 1) ? a_cur[i].y
                             : (kk == 2) ? a_cur[i].z : a_cur[i].w;
                    acc[i][0] += av * b0.x; acc[i][1] += av * b0.y;
                    acc[i][2] += av * b0.z; acc[i][3] += av * b0.w;
                    acc[i][4] += av * b1.x; acc[i][5] += av * b1.y;
                    acc[i][6] += av * b1.z; acc[i][7] += av * b1.w;
                }
            }
#pragma unroll
            for (int i = 0; i < 4; ++i) a_cur[i] = a_nxt[i];
        }
        // last k4 chunk (k4 = 28)
#pragma unroll
        for (int kk = 0; kk < 4; ++kk) {
            float4 b0 = *(const float4*)(Wl + (28 + kk) * 128 + c0);
            float4 b1 = *(const float4*)(Wl + (28 + kk) * 128 + c0 + 64);
#pragma unroll
            for (int i = 0; i < 4; ++i) {
                float av = (kk == 0) ? a_cur[i].x : (kk == 1) ? a_cur[i].y
                         : (kk == 2) ? a_cur[i].z : a_cur[i].w;
                acc[i][0] += av * b0.x; acc[i][1] += av * b0.y;
                acc[i][2] += av * b0.z; acc[i][3] += av * b0.w;
                acc[i][4] += av * b1.x; acc[i][5] += av * b1.y;
                acc[i][6] += av * b1.z; acc[i][7] += av * b1.w;
            }
        }
        __syncthreads();
    }

#pragma unroll
    for (int i = 0; i < 4; ++i) {
        int r = r0 + i;
        if (r < n) {
            float dv = dinv[r];
            float4 o0, o1;
            o0.x = acc[i][0] * dv; o0.y = acc[i][1] * dv;
            o0.z = acc[i][2] * dv; o0.w = acc[i][3] * dv;
            o1.x = acc[i][4] * dv; o1.y = acc[i][5] * dv;
            o1.z = acc[i][6] * dv; o1.w = acc[i][7] * dv;
            *(float4*)(G + (size_t)r * 128 + c0) = o0;
            *(float4*)(G + (size_t)r * 128 + c0 + 64) = o1;
        }
    }
}

// ---------------------------------------------------------------------------
// Gather-aggregate + bias + relu. 32 lanes per node (float4 over 128 dims),
// 8 nodes per 256-thread block. acc init = g[v] (self loop).
// 4-unrolled edge loop: 4 independent 512B row loads in flight per half-wave
// + dual accumulator trees (R2 was latency-bound: VALUBusy 11%, hbm 49%).
// ---------------------------------------------------------------------------
__global__ __launch_bounds__(256) void k_gather_relu(const float* __restrict__ G,
                                                     const int* __restrict__ srcs,
                                                     const int* __restrict__ row_start,
                                                     const int* __restrict__ cnt,
                                                     const float* __restrict__ dinv,
                                                     const float* __restrict__ bias,
                                                     float* __restrict__ Z, int n) {
    int v = blockIdx.x * 8 + (threadIdx.x >> 5);
    int lane = threadIdx.x & 31;
    if (v >= n) return;
    const float4* G4 = (const float4*)G;
    float4 acc = G4[(size_t)v * 32 + lane];  // self loop
    float4 acc2 = {0.f, 0.f, 0.f, 0.f};
    int beg = row_start[v], deg = cnt[v];
    int e = 0;
    for (; e + 3 < deg; e += 4) {
        int s0 = srcs[beg + e];
        int s1 = srcs[beg + e + 1];
        int s2 = srcs[beg + e + 2];
        int s3 = srcs[beg + e + 3];
        float4 t0 = G4[(size_t)s0 * 32 + lane];
        float4 t1 = G4[(size_t)s1 * 32 + lane];
        float4 t2 = G4[(size_t)s2 * 32 + lane];
        float4 t3 = G4[(size_t)s3 * 32 + lane];
        acc.x += t0.x + t1.x; acc.y += t0.y + t1.y;
        acc.z += t0.z + t1.z; acc.w += t0.w + t1.w;
        acc2.x += t2.x + t3.x; acc2.y += t2.y + t3.y;
        acc2.z += t2.z + t3.z; acc2.w += t2.w + t3.w;
    }
    for (; e < deg; ++e) {
        int s0 = srcs[beg + e];
        float4 t0 = G4[(size_t)s0 * 32 + lane];
        acc.x += t0.x; acc.y += t0.y; acc.z += t0.z; acc.w += t0.w;
    }
    acc.x += acc2.x; acc.y += acc2.y; acc.z += acc2.z; acc.w += acc2.w;
    float dv = dinv[v];
    const float4* b4 = (const float4*)bias;
    float4 bb = b4[lane];
    float4 z;
    z.x = fmaxf(dv * acc.x + bb.x, 0.f);
    z.y = fmaxf(dv * acc.y + bb.y, 0.f);
    z.z = fmaxf(dv * acc.z + bb.z, 0.f);
    z.w = fmaxf(dv * acc.w + bb.w, 0.f);
    ((float4*)Z)[(size_t)v * 32 + lane] = z;
}

// ---------------------------------------------------------------------------
// Decode: out[e] = dot(Z[s_e], Z[d_e]) over 128 dims. 32 lanes/edge.
// ---------------------------------------------------------------------------
__global__ __launch_bounds__(256) void k_decode(const float* __restrict__ Z,
                                                const int* __restrict__ eli,
                                                float* __restrict__ out, int el) {
    int sub = threadIdx.x >> 5, lane = threadIdx.x & 31;
    int e = blockIdx.x * 8 + sub;
    if (e >= el) return;
    int s = eli[e], d = eli[el + e];
    const float4* Z4 = (const float4*)Z;
    float4 a = Z4[(size_t)s * 32 + lane];
    float4 b = Z4[(size_t)d * 32 + lane];
    float dot = a.x * b.x + a.y * b.y + a.z * b.z + a.w * b.w;
#pragma unroll
    for (int off = 16; off; off >>= 1) dot += __shfl_down(dot, off, 32);
    if (lane == 0) out[e] = dot;
}

extern "C" void kernel_launch(void* const* d_in, const int* in_sizes, int n_in,
                              void* d_out, int out_size, void* d_ws, size_t ws_size,
                              hipStream_t stream) {
    const float* x  = (const float*)d_in[0];
    const int*  ei  = (const int*)d_in[1];
    const int*  eli = (const int*)d_in[2];
    const float* W1 = (const float*)d_in[3];
    const float* b1 = (const float*)d_in[4];
    const float* W2 = (const float*)d_in[5];
    const float* b2 = (const float*)d_in[6];
    float* out = (float*)d_out;

    const int N  = in_sizes[0] / 128;
    const int E  = in_sizes[1] / 2;
    const int EL = in_sizes[2] / 2;
    const int* src = ei;
    const int* dst = ei + E;

    char* ws = (char*)d_ws;
    size_t off = 0;
    auto alloc = [&](size_t bytes) -> void* {
        void* p = ws + off;
        off += bytes;
        off = (off + 255) & ~(size_t)255;
        return p;
    };
    int*   cnt       = (int*)alloc((size_t)N * 4);
    int*   fill      = (int*)alloc((size_t)N * 4);
    int*   row_start = (int*)alloc((size_t)N * 4);
    float* dinv      = (float*)alloc((size_t)N * 4);
    int*   bsum      = (int*)alloc(4096);
    int*   srcs      = (int*)alloc((size_t)E * 4);
    float* buf0      = (float*)alloc((size_t)N * 128 * 4);
    float* buf1      = (float*)alloc((size_t)N * 128 * 4);

    const int nb = (N + 1023) / 1024;

    k_zero<<<(N + 255) / 256, 256, 0, stream>>>(cnt, N);
    k_zero<<<(N + 255) / 256, 256, 0, stream>>>(fill, N);
    k_hist<<<(E + 255) / 256, 256, 0, stream>>>(dst, cnt, E);
    k_scan1<<<nb, 1024, 0, stream>>>(cnt, row_start, bsum, N);
    k_scan2<<<1, 1024, 0, stream>>>(bsum, nb);
    k_scan3<<<(N + 255) / 256, 256, 0, stream>>>(row_start, bsum, cnt, dinv, N);
    k_scatter<<<(E + 255) / 256, 256, 0, stream>>>(src, dst, row_start, fill, srcs, E);

    // layer 1: g1 = (x@W1)*dinv -> buf0 ; z1 -> buf1
    k_gemm_scale<<<(N + 63) / 64, 256, 0, stream>>>(x, W1, dinv, buf0, N);
    k_gather_relu<<<(N + 7) / 8, 256, 0, stream>>>(buf0, srcs, row_start, cnt, dinv, b1, buf1, N);
    // layer 2: g2 = (z1@W2)*dinv -> buf0 ; z2 -> buf1
    k_gemm_scale<<<(N + 63) / 64, 256, 0, stream>>>(buf1, W2, dinv, buf0, N);
    k_gather_relu<<<(N + 7) / 8, 256, 0, stream>>>(buf0, srcs, row_start, cnt, dinv, b2, buf1, N);
    // decode
    k_decode<<<(EL + 7) / 8, 256, 0, stream>>>(buf1, eli, out, EL);
}

// Round 4
// 473.416 us; speedup vs baseline: 1.3112x; 1.3112x over previous
//
#include <hip/hip_runtime.h>
#include <hip/hip_bf16.h>
#include <hip/hip_fp16.h>

// ---------------------------------------------------------------------------
// GCN link predictor, fp16 intermediate buffers (fp32 accumulate everywhere):
//   dinv[v] = rsqrt(indeg(v)+1)
//   g  = (X @ W) * dinv[row]            (fused in GEMM epilogue, stored fp16)
//   z  = relu(dinv[v]*(g[v] + sum_{s->v} g[s]) + b)   (CSR gather, stored fp16)
//   out[e] = dot(z2[s_e], z2[d_e])      (fp32 accumulate)
// CSR (edges sorted by dst) built per call: histogram -> scan -> scatter.
// R3 lesson: gather is bandwidth-bound on random row segments (~3.7 TB/s
// service rate regardless of MLP) -> halve the bytes with fp16 rows (256 B).
// ---------------------------------------------------------------------------

typedef _Float16 half8 __attribute__((ext_vector_type(8)));
typedef _Float16 half4 __attribute__((ext_vector_type(4)));

__global__ __launch_bounds__(256) void k_zero(int* __restrict__ p, int n) {
    int i = blockIdx.x * 256 + threadIdx.x;
    if (i < n) p[i] = 0;
}

__global__ __launch_bounds__(256) void k_hist(const int* __restrict__ dst,
                                              int* __restrict__ cnt, int E) {
    int e = blockIdx.x * 256 + threadIdx.x;
    if (e < E) atomicAdd(&cnt[dst[e]], 1);
}

// block-level inclusive scan -> exclusive row_start + block sums
__global__ __launch_bounds__(1024) void k_scan1(const int* __restrict__ cnt,
                                                int* __restrict__ row_start,
                                                int* __restrict__ bsum, int n) {
    __shared__ int sh[1024];
    int tid = threadIdx.x;
    int i = blockIdx.x * 1024 + tid;
    int v = (i < n) ? cnt[i] : 0;
    sh[tid] = v;
    __syncthreads();
    for (int off = 1; off < 1024; off <<= 1) {
        int t = (tid >= off) ? sh[tid - off] : 0;
        __syncthreads();
        sh[tid] += t;
        __syncthreads();
    }
    if (i < n) row_start[i] = sh[tid] - v;
    if (tid == 1023) bsum[blockIdx.x] = sh[tid];
}

// exclusive scan of block sums (nb <= 1024)
__global__ __launch_bounds__(1024) void k_scan2(int* __restrict__ bsum, int nb) {
    __shared__ int sh[1024];
    int tid = threadIdx.x;
    int v = (tid < nb) ? bsum[tid] : 0;
    sh[tid] = v;
    __syncthreads();
    for (int off = 1; off < 1024; off <<= 1) {
        int t = (tid >= off) ? sh[tid - off] : 0;
        __syncthreads();
        sh[tid] += t;
        __syncthreads();
    }
    if (tid < nb) bsum[tid] = sh[tid] - v;
}

// add block offsets + compute dinv = rsqrt(deg+1)  (deg includes self loop)
__global__ __launch_bounds__(256) void k_scan3(int* __restrict__ row_start,
                                               const int* __restrict__ bsum,
                                               const int* __restrict__ cnt,
                                               float* __restrict__ dinv, int n) {
    int i = blockIdx.x * 256 + threadIdx.x;
    if (i < n) {
        row_start[i] += bsum[i >> 10];
        dinv[i] = rsqrtf((float)cnt[i] + 1.0f);
    }
}

__global__ __launch_bounds__(256) void k_scatter(const int* __restrict__ src,
                                                 const int* __restrict__ dst,
                                                 const int* __restrict__ row_start,
                                                 int* __restrict__ fill,
                                                 int* __restrict__ srcs, int E) {
    int e = blockIdx.x * 256 + threadIdx.x;
    if (e < E) {
        int d = dst[e];
        int p = row_start[d] + atomicAdd(&fill[d], 1);
        srcs[p] = src[e];
    }
}

// ---------------------------------------------------------------------------
// GEMM: G[r][c] = dinv[r] * sum_k A[r][k]*W[k][c]    (N x 128) @ (128 x 128)
// A is fp32 (layer 1: x) or fp16 (layer 2: z1). Output G is fp16.
// Block: 64 rows x 128 cols, 256 threads; thread tile 4 rows x 8 cols.
// W (fp32) staged in 32-k chunks (16 KB LDS). A broadcast-loaded from global,
// software-pipelined. __launch_bounds__(256,4) caps VGPRs at 128 (no spill).
// ---------------------------------------------------------------------------
template <typename AT>
__global__ __launch_bounds__(256, 4) void k_gemm_scale(const AT* __restrict__ X,
                                                       const float* __restrict__ W,
                                                       const float* __restrict__ dinv,
                                                       _Float16* __restrict__ G, int n) {
    __shared__ float Wl[32 * 128];
    const int tid = threadIdx.x;
    const int colgrp = tid & 15;   // 16 col groups
    const int rowgrp = tid >> 4;   // 16 row groups
    const int r0 = blockIdx.x * 64 + rowgrp * 4;
    const int c0 = colgrp * 4;     // second col block at c0+64

    const AT* Xr[4];
#pragma unroll
    for (int i = 0; i < 4; ++i) {
        int r = r0 + i;
        if (r >= n) r = n - 1;  // clamp: harmless duplicate load
        Xr[i] = X + (size_t)r * 128;
    }

    float acc[4][8] = {};

    auto loadA = [](const AT* p) -> float4 {
        if constexpr (sizeof(AT) == 4) {
            return *(const float4*)p;
        } else {
            half4 h = *(const half4*)p;
            float4 f;
            f.x = (float)h[0]; f.y = (float)h[1];
            f.z = (float)h[2]; f.w = (float)h[3];
            return f;
        }
    };

    for (int kc = 0; kc < 128; kc += 32) {
        {
            const float4* W4 = (const float4*)(W + (size_t)kc * 128);
            float4* Wl4 = (float4*)Wl;
#pragma unroll
            for (int it = 0; it < 4; ++it)
                Wl4[it * 256 + tid] = W4[it * 256 + tid];
        }
        __syncthreads();

        float4 a_cur[4], a_nxt[4];
#pragma unroll
        for (int i = 0; i < 4; ++i) a_cur[i] = loadA(Xr[i] + kc);

#pragma unroll 1
        for (int k4 = 0; k4 < 28; k4 += 4) {
#pragma unroll
            for (int i = 0; i < 4; ++i) a_nxt[i] = loadA(Xr[i] + kc + k4 + 4);
#pragma unroll
            for (int kk = 0; kk < 4; ++kk) {
                float4 b0 = *(const float4*)(Wl + (k4 + kk) * 128 + c0);
                float4 b1 = *(const float4*)(Wl + (k4 + kk) * 128 + c0 + 64);
#pragma unroll
                for (int i = 0; i < 4; ++i) {
                    float av = (kk == 0) ? a_cur[i].x : (kk == 1) ? a_cur[i].y
                             : (kk == 2) ? a_cur[i].z : a_cur[i].w;
                    acc[i][0] += av * b0.x; acc[i][1] += av * b0.y;
                    acc[i][2] += av * b0.z; acc[i][3] += av * b0.w;
                    acc[i][4] += av * b1.x; acc[i][5] += av * b1.y;
                    acc[i][6] += av * b1.z; acc[i][7] += av * b1.w;
                }
            }
#pragma unroll
            for (int i = 0; i < 4; ++i) a_cur[i] = a_nxt[i];
        }
#pragma unroll
        for (int kk = 0; kk < 4; ++kk) {
            float4 b0 = *(const float4*)(Wl + (28 + kk) * 128 + c0);
            float4 b1 = *(const float4*)(Wl + (28 + kk) * 128 + c0 + 64);
#pragma unroll
            for (int i = 0; i < 4; ++i) {
                float av = (kk == 0) ? a_cur[i].x : (kk == 1) ? a_cur[i].y
                         : (kk == 2) ? a_cur[i].z : a_cur[i].w;
                acc[i][0] += av * b0.x; acc[i][1] += av * b0.y;
                acc[i][2] += av * b0.z; acc[i][3] += av * b0.w;
                acc[i][4] += av * b1.x; acc[i][5] += av * b1.y;
                acc[i][6] += av * b1.z; acc[i][7] += av * b1.w;
            }
        }
        __syncthreads();
    }

#pragma unroll
    for (int i = 0; i < 4; ++i) {
        int r = r0 + i;
        if (r < n) {
            float dv = dinv[r];
            half4 o0, o1;
#pragma unroll
            for (int j = 0; j < 4; ++j) {
                o0[j] = (_Float16)(acc[i][j] * dv);
                o1[j] = (_Float16)(acc[i][4 + j] * dv);
            }
            *(half4*)(G + (size_t)r * 128 + c0) = o0;
            *(half4*)(G + (size_t)r * 128 + c0 + 64) = o1;
        }
    }
}

// ---------------------------------------------------------------------------
// Gather-aggregate + bias + relu. 16 lanes per node (half8 over 128 dims),
// 16 nodes per 256-thread block. acc init = g[v] (self loop), fp32 accum.
// Unroll 4 with dual accumulator trees.
// ---------------------------------------------------------------------------
__global__ __launch_bounds__(256) void k_gather_relu(const _Float16* __restrict__ G,
                                                     const int* __restrict__ srcs,
                                                     const int* __restrict__ row_start,
                                                     const int* __restrict__ cnt,
                                                     const float* __restrict__ dinv,
                                                     const float* __restrict__ bias,
                                                     _Float16* __restrict__ Z, int n) {
    int v = blockIdx.x * 16 + (threadIdx.x >> 4);
    int lane = threadIdx.x & 15;
    if (v >= n) return;
    const half8* G8 = (const half8*)G;

    half8 self = G8[(size_t)v * 16 + lane];
    float acc[8], acc2[8];
#pragma unroll
    for (int j = 0; j < 8; ++j) { acc[j] = (float)self[j]; acc2[j] = 0.f; }

    int beg = row_start[v], deg = cnt[v];
    int e = 0;
    for (; e + 3 < deg; e += 4) {
        int s0 = srcs[beg + e];
        int s1 = srcs[beg + e + 1];
        int s2 = srcs[beg + e + 2];
        int s3 = srcs[beg + e + 3];
        half8 t0 = G8[(size_t)s0 * 16 + lane];
        half8 t1 = G8[(size_t)s1 * 16 + lane];
        half8 t2 = G8[(size_t)s2 * 16 + lane];
        half8 t3 = G8[(size_t)s3 * 16 + lane];
#pragma unroll
        for (int j = 0; j < 8; ++j) {
            acc[j]  += (float)t0[j] + (float)t1[j];
            acc2[j] += (float)t2[j] + (float)t3[j];
        }
    }
    for (; e < deg; ++e) {
        int s0 = srcs[beg + e];
        half8 t0 = G8[(size_t)s0 * 16 + lane];
#pragma unroll
        for (int j = 0; j < 8; ++j) acc[j] += (float)t0[j];
    }

    float dv = dinv[v];
    const float4* b4 = (const float4*)bias;
    float4 bb0 = b4[lane * 2], bb1 = b4[lane * 2 + 1];
    float bf[8] = {bb0.x, bb0.y, bb0.z, bb0.w, bb1.x, bb1.y, bb1.z, bb1.w};
    half8 zo;
#pragma unroll
    for (int j = 0; j < 8; ++j) {
        float z = dv * (acc[j] + acc2[j]) + bf[j];
        zo[j] = (_Float16)fmaxf(z, 0.f);
    }
    ((half8*)Z)[(size_t)v * 16 + lane] = zo;
}

// ---------------------------------------------------------------------------
// Decode: out[e] = dot(Z[s_e], Z[d_e]) over 128 dims (fp16 rows, fp32 accum).
// 16 lanes/edge, 16 edges per 256-thread block.
// ---------------------------------------------------------------------------
__global__ __launch_bounds__(256) void k_decode(const _Float16* __restrict__ Z,
                                                const int* __restrict__ eli,
                                                float* __restrict__ out, int el) {
    int sub = threadIdx.x >> 4, lane = threadIdx.x & 15;
    int e = blockIdx.x * 16 + sub;
    if (e >= el) return;
    int s = eli[e], d = eli[el + e];
    const half8* Z8 = (const half8*)Z;
    half8 a = Z8[(size_t)s * 16 + lane];
    half8 b = Z8[(size_t)d * 16 + lane];
    float dot = 0.f;
#pragma unroll
    for (int j = 0; j < 8; ++j) dot += (float)a[j] * (float)b[j];
#pragma unroll
    for (int off = 8; off; off >>= 1) dot += __shfl_down(dot, off, 16);
    if (lane == 0) out[e] = dot;
}

extern "C" void kernel_launch(void* const* d_in, const int* in_sizes, int n_in,
                              void* d_out, int out_size, void* d_ws, size_t ws_size,
                              hipStream_t stream) {
    const float* x  = (const float*)d_in[0];
    const int*  ei  = (const int*)d_in[1];
    const int*  eli = (const int*)d_in[2];
    const float* W1 = (const float*)d_in[3];
    const float* b1 = (const float*)d_in[4];
    const float* W2 = (const float*)d_in[5];
    const float* b2 = (const float*)d_in[6];
    float* out = (float*)d_out;

    const int N  = in_sizes[0] / 128;
    const int E  = in_sizes[1] / 2;
    const int EL = in_sizes[2] / 2;
    const int* src = ei;
    const int* dst = ei + E;

    char* ws = (char*)d_ws;
    size_t off = 0;
    auto alloc = [&](size_t bytes) -> void* {
        void* p = ws + off;
        off += bytes;
        off = (off + 255) & ~(size_t)255;
        return p;
    };
    int*       cnt       = (int*)alloc((size_t)N * 4);
    int*       fill      = (int*)alloc((size_t)N * 4);
    int*       row_start = (int*)alloc((size_t)N * 4);
    float*     dinv      = (float*)alloc((size_t)N * 4);
    int*       bsum      = (int*)alloc(4096);
    int*       srcs      = (int*)alloc((size_t)E * 4);
    _Float16*  buf0      = (_Float16*)alloc((size_t)N * 128 * 2);  // G (pre-agg)
    _Float16*  buf1      = (_Float16*)alloc((size_t)N * 128 * 2);  // Z (post-agg)

    const int nb = (N + 1023) / 1024;

    k_zero<<<(N + 255) / 256, 256, 0, stream>>>(cnt, N);
    k_zero<<<(N + 255) / 256, 256, 0, stream>>>(fill, N);
    k_hist<<<(E + 255) / 256, 256, 0, stream>>>(dst, cnt, E);
    k_scan1<<<nb, 1024, 0, stream>>>(cnt, row_start, bsum, N);
    k_scan2<<<1, 1024, 0, stream>>>(bsum, nb);
    k_scan3<<<(N + 255) / 256, 256, 0, stream>>>(row_start, bsum, cnt, dinv, N);
    k_scatter<<<(E + 255) / 256, 256, 0, stream>>>(src, dst, row_start, fill, srcs, E);

    // layer 1: g1 = (x@W1)*dinv -> buf0 (fp16) ; z1 -> buf1 (fp16)
    k_gemm_scale<float><<<(N + 63) / 64, 256, 0, stream>>>(x, W1, dinv, buf0, N);
    k_gather_relu<<<(N + 15) / 16, 256, 0, stream>>>(buf0, srcs, row_start, cnt, dinv, b1, buf1, N);
    // layer 2: g2 = (z1@W2)*dinv -> buf0 ; z2 -> buf1
    k_gemm_scale<_Float16><<<(N + 63) / 64, 256, 0, stream>>>(buf1, W2, dinv, buf0, N);
    k_gather_relu<<<(N + 15) / 16, 256, 0, stream>>>(buf0, srcs, row_start, cnt, dinv, b2, buf1, N);
    // decode
    k_decode<<<(EL + 15) / 16, 256, 0, stream>>>(buf1, eli, out, EL);
}